// Round 8
// baseline (119.360 us; speedup 1.0000x reference)
//
#include <hip/hip_runtime.h>

typedef unsigned int u32;
typedef unsigned short u16;

#define Cn 128
#define ICn 64
#define Nn 4096
#define Mn 1024

typedef __attribute__((ext_vector_type(8))) short s8v;   // 8 bf16 (4 VGPRs)
typedef __attribute__((ext_vector_type(4))) float f4v;   // 4 fp32 acc

union U8 { uint4 u; s8v v; };

__device__ __forceinline__ float asf(u32 u){ union{u32 i; float f;} v; v.i = u; return v.f; }
__device__ __forceinline__ float bf2f(u16 u){ return asf(((u32)u) << 16); }
// HW packed f32->bf16 (RNE)
__device__ __forceinline__ u32 pk2(float lo, float hi){
    u32 r;
    asm("v_cvt_pk_bf16_f32 %0, %1, %2" : "=v"(r) : "v"(lo), "v"(hi));
    return r;
}
__device__ __forceinline__ u16 f2bf(float f){ return (u16)pk2(f, f); }

// ---------------------------------------------------------------------------
// K1: per (row-pair r, half-width wb, batch b):
//   stage x^T bf16 (swizzled), W1/W4 bf16, u3 = w5[:64].W3;
//   dual conv MFMA -> pool a1 -> xg_o (bf16, *(1/1024) fold), pool a4 -> p_o;
//   t_o = u3.x + c3.  (unchanged from R7 — verified)
// ---------------------------------------------------------------------------
__global__ __launch_bounds__(256) void k_conv(
    const float* __restrict__ x,
    const float* __restrict__ w1, const float* __restrict__ b1,
    const float* __restrict__ w3, const float* __restrict__ b3,
    const float* __restrict__ w4, const float* __restrict__ b4,
    const float* __restrict__ w5,
    float* __restrict__ t_o, float* __restrict__ p_o, u16* __restrict__ xg_o)
{
    const int tile = blockIdx.x;   // 0..63
    const int r  = tile >> 1;      // row-pair 0..31
    const int wb = tile & 1;       // half-width 0..1
    const int b  = blockIdx.y;
    const int tid = threadIdx.x;

    __shared__ __align__(16) u16 smem[35080];
    u16* xsT = smem;                    // [64][136]
    u16* w1t = smem + 8704;             // [64][136]
    u16* w4t = smem + 17408;            // [64][136]
    float* u3s = (float*)&smem[26112];  // [129]
    float* ph0 = (float*)&smem[26372];  // [32][68]
    float* ph1 = (float*)&smem[30724];  // [32][68]

    // ---- stage x^T as bf16 channel-pairs, swizzled ----
    #pragma unroll
    for (int it = 0; it < 4; ++it) {
        int f = tid + 256 * it;        // 1024 tasks: cp = f>>4, rem = f&15
        int cp = f >> 4, rem = f & 15;
        int rl = rem >> 3, wq = rem & 7;
        const float* src = x + ((size_t)(b * Cn + 2 * cp)) * Nn + (2 * r + rl) * 64 + 32 * wb + 4 * wq;
        float4 v0 = *(const float4*)src;
        float4 v1 = *(const float4*)(src + Nn);
        int lp0 = rl * 32 + 4 * wq;
        int cS = (2 * cp) ^ (wq << 3);
        *(u32*)&xsT[(lp0 + 0) * 136 + cS] = pk2(v0.x, v1.x);
        *(u32*)&xsT[(lp0 + 1) * 136 + cS] = pk2(v0.y, v1.y);
        *(u32*)&xsT[(lp0 + 2) * 136 + cS] = pk2(v0.z, v1.z);
        *(u32*)&xsT[(lp0 + 3) * 136 + cS] = pk2(v0.w, v1.w);
    }
    // ---- stage W1, W4 ----
    #pragma unroll
    for (int it = 0; it < 4; ++it) {
        int f = tid + 256 * it;        // 1024 groups of 8: ic = f>>4, cq = f&15
        int ic = f >> 4, cq = f & 15;
        const float4* s1 = (const float4*)&w1[f * 8];
        const float4* s4 = (const float4*)&w4[f * 8];
        float4 a0 = s1[0], a1v = s1[1];
        float4 d0 = s4[0], d1v = s4[1];
        uint4 A, D;
        A.x = pk2(a0.x, a0.y); A.y = pk2(a0.z, a0.w); A.z = pk2(a1v.x, a1v.y); A.w = pk2(a1v.z, a1v.w);
        D.x = pk2(d0.x, d0.y); D.y = pk2(d0.z, d0.w); D.z = pk2(d1v.x, d1v.y); D.w = pk2(d1v.z, d1v.w);
        *(uint4*)&w1t[ic * 136 + 8 * cq] = A;
        *(uint4*)&w4t[ic * 136 + 8 * cq] = D;
    }
    // ---- u3 = w5[:64].W3 ----
    if (tid < 128) {
        float s0 = 0.f, s1 = 0.f;
        #pragma unroll 8
        for (int ic = 0; ic < 64; ic += 2) {
            s0 += w5[ic]     * w3[ic * Cn + tid];
            s1 += w5[ic + 1] * w3[(ic + 1) * Cn + tid];
        }
        u3s[tid] = s0 + s1;
    } else if (tid == 128) {
        float s = 0.f;
        #pragma unroll 16
        for (int ic = 0; ic < 64; ++ic) s += w5[ic] * b3[ic];
        u3s[128] = s;
    }
    __syncthreads();

    const int lane = tid & 63;
    const int wv   = tid >> 6;
    const int col  = lane & 15;
    const int quad = lane >> 4;

    // ---- dual conv MFMA: D[ic][lp] ----
    f4v acc1[4] = {}, acc4[4] = {};
    const u16* xrow = &xsT[(16 * wv + col) * 136];
    const int xsw = (((16 * wv + col) >> 2) & 7) << 3;
    #pragma unroll
    for (int kb = 0; kb < 4; ++kb) {
        s8v bx = *(const s8v*)&xrow[(kb * 32 + quad * 8) ^ xsw];
        #pragma unroll
        for (int icb = 0; icb < 4; ++icb) {
            s8v a1 = *(const s8v*)&w1t[(icb * 16 + col) * 136 + kb * 32 + quad * 8];
            s8v a4 = *(const s8v*)&w4t[(icb * 16 + col) * 136 + kb * 32 + quad * 8];
            acc1[icb] = __builtin_amdgcn_mfma_f32_16x16x32_bf16(a1, bx, acc1[icb], 0, 0, 0);
            acc4[icb] = __builtin_amdgcn_mfma_f32_16x16x32_bf16(a4, bx, acc4[icb], 0, 0, 0);
        }
    }

    // ---- both horizontal pair-max pools (a1->ph0, a4->ph1), one phase ----
    const int lp = 16 * wv + col;
    const int rl = lp >> 5, wl = lp & 31, pw = wl >> 1;
    const bool wr = (wl & 1) == 0;
    #pragma unroll
    for (int icb = 0; icb < 4; ++icb)
        #pragma unroll
        for (int reg = 0; reg < 4; ++reg) {
            float v1 = acc1[icb][reg];
            float m1 = fmaxf(v1, __shfl_xor(v1, 1, 64));
            float v4 = acc4[icb][reg];
            float m4 = fmaxf(v4, __shfl_xor(v4, 1, 64));
            if (wr) {
                ph0[(rl * 16 + pw) * 68 + icb * 16 + quad * 4 + reg] = m1;
                ph1[(rl * 16 + pw) * 68 + icb * 16 + quad * 4 + reg] = m4;
            }
        }
    __syncthreads();   // MFMA LDS reads done + ph ready

    // ---- xg_o = (vpool(a1) + b1) / 1024 as bf16 ----
    #pragma unroll
    for (int it = 0; it < 4; ++it) {
        int e = tid + 256 * it;        // 1024: pwq = e>>6, ic = e&63
        int pwq = e >> 6, ic = e & 63;
        float v = fmaxf(ph0[pwq * 68 + ic], ph0[(16 + pwq) * 68 + ic]) + b1[ic];
        xg_o[((size_t)(b * 64 + ic) << 10) + r * 32 + wb * 16 + pwq] = f2bf(v * (1.0f / 1024.0f));
    }
    // ---- t = u3.x + c3, all 256 threads (4 lanes per pixel) ----
    {
        int px = tid >> 2, part = tid & 3;
        const int tsw = ((px >> 2) & 7) << 3;
        const u16* xr = &xsT[px * 136];
        float s = 0.f;
        #pragma unroll
        for (int cq = 0; cq < 4; ++cq) {
            int u = part * 32 + cq * 8;
            s8v xv = *(const s8v*)&xr[u ^ tsw];
            #pragma unroll
            for (int j = 0; j < 8; ++j) s += u3s[u + j] * bf2f((u16)xv[j]);
        }
        s += __shfl_xor(s, 1, 64);
        s += __shfl_xor(s, 2, 64);
        if (part == 0)
            t_o[(size_t)b * Nn + (2 * r + (px >> 5)) * 64 + 32 * wb + (px & 31)] = s + u3s[128];
    }
    // ---- p from a4 pool ----
    if (tid < 16) {
        float s = 0.f;
        #pragma unroll 8
        for (int ic = 0; ic < 64; ++ic) {
            float pv = fmaxf(ph1[tid * 68 + ic], ph1[(16 + tid) * 68 + ic]) + b4[ic];
            s += w5[64 + ic] * pv;
        }
        p_o[(size_t)b * Mn + r * 32 + wb * 16 + tid] = s;
    }
}

// ---------------------------------------------------------------------------
// K2: grid (32 n-tiles, 8 b) x 512 thr. matmul1 (feats hi+lo x xg) ->
// y packed bf16 hi/lo -> matmul2 (w2 x y) -> NEW: acc2 staged to LDS
// ytr[128 co][132 n] f32, then fully-coalesced float4 RMW epilogue
// (was: scalar 4B stores at 16KB stride = ~25% coalescing on 32 MB).
// ---------------------------------------------------------------------------
__global__ __launch_bounds__(512) void k_back(
    const float* __restrict__ x, const float* __restrict__ t,
    const float* __restrict__ p, const u16* __restrict__ xg,
    const float* __restrict__ w2, const float* __restrict__ b2,
    const float* __restrict__ gamma, const float* __restrict__ beta,
    const float* __restrict__ mean, const float* __restrict__ var,
    float* __restrict__ out)
{
    const int nt = blockIdx.x;     // 0..31
    const int b  = blockIdx.y;
    const int tid = threadIdx.x;

    __shared__ __align__(16) char smem[87808];
    u16* xgs  = (u16*)smem;                  // [2][64*128]
    u16* w2t  = (u16*)(smem + 32768);        // [128*64]
    u32* ylds = (u32*)(smem + 49152);        // [64*129]
    float* pl = (float*)(smem + 82176);      // [1024]
    float* tl = (float*)(smem + 86272);      // [128]
    float* sc0 = (float*)(smem + 86784);     // [128]
    float* sc1 = (float*)(smem + 87296);     // [128]
    float* ytr = (float*)smem;               // epilogue: [128][132] f32 (67584 B)

    // ---- phase 0 staging ----
    pl[tid]       = p[b * Mn + tid];
    pl[tid + 512] = p[b * Mn + tid + 512];
    if (tid < 128) {
        tl[tid] = t[(size_t)b * Nn + nt * 128 + tid];
    } else if (tid < 256) {
        int co = tid - 128;
        float s = gamma[co] * rsqrtf(var[co] + 1e-5f);
        sc0[co] = s;
        sc1[co] = (b2[co] - mean[co]) * s + beta[co];
    }
    #pragma unroll
    for (int it = 0; it < 2; ++it) {
        int f = tid + 512 * it;            // 1024 chunks: co = f>>3, iq = f&7
        int co = f >> 3, iq = f & 7;
        const float4* s2 = (const float4*)&w2[co * 64 + iq * 8];
        float4 a0 = s2[0], a1v = s2[1];
        uint4 V;
        V.x = pk2(a0.x, a0.y); V.y = pk2(a0.z, a0.w); V.z = pk2(a1v.x, a1v.y); V.w = pk2(a1v.z, a1v.w);
        *(uint4*)&w2t[co * 64 + ((iq * 8) ^ ((co & 7) << 3))] = V;
    }
    #pragma unroll
    for (int it = 0; it < 2; ++it) {
        int f = tid + 512 * it;            // 1024 chunks: ic = f>>4, mc = f&15
        int ic = f >> 4, mc = f & 15;
        uint4 V = *(const uint4*)&xg[((size_t)(b * 64 + ic) << 10) + mc * 8];
        *(uint4*)&xgs[ic * 128 + ((mc * 8) ^ ((ic & 7) << 3))] = V;
    }
    __syncthreads();

    const int lane = tid & 63;
    const int wv   = tid >> 6;         // 0..7
    const int col  = lane & 15;
    const int quad = lane >> 4;
    const int nb   = wv * 16;
    const int xsw  = (col & 7) << 3;
    const float tval = tl[nb + col];

    // ---- matmul1: y[n][ic] += (hi+lo)(feats) x xg, m-tiles of 128 ----
    f4v acc[4] = {};
    for (int mt = 0; mt < 8; ++mt) {
        uint4 pf0, pf1;
        if (mt < 7) {
            int f0 = tid, f1 = tid + 512;
            pf0 = *(const uint4*)&xg[((size_t)(b * 64 + (f0 >> 4)) << 10) + (mt + 1) * 128 + (f0 & 15) * 8];
            pf1 = *(const uint4*)&xg[((size_t)(b * 64 + (f1 >> 4)) << 10) + (mt + 1) * 128 + (f1 & 15) * 8];
        }
        const u16* xb = xgs + (mt & 1) * 8192;
        #pragma unroll
        for (int kb = 0; kb < 4; ++kb) {
            int mb = mt * 128 + kb * 32;
            float4 pa = *(const float4*)&pl[mb + quad * 8];
            float4 pb = *(const float4*)&pl[mb + quad * 8 + 4];
            float f0 = fmaxf(tval + pa.x, 0.f), f1 = fmaxf(tval + pa.y, 0.f);
            float f2 = fmaxf(tval + pa.z, 0.f), f3 = fmaxf(tval + pa.w, 0.f);
            float f4 = fmaxf(tval + pb.x, 0.f), f5 = fmaxf(tval + pb.y, 0.f);
            float f6 = fmaxf(tval + pb.z, 0.f), f7 = fmaxf(tval + pb.w, 0.f);
            U8 hi, lo;
            hi.u.x = pk2(f0, f1); hi.u.y = pk2(f2, f3); hi.u.z = pk2(f4, f5); hi.u.w = pk2(f6, f7);
            float l0 = f0 - asf(hi.u.x << 16), l1 = f1 - asf(hi.u.x & 0xffff0000u);
            float l2 = f2 - asf(hi.u.y << 16), l3 = f3 - asf(hi.u.y & 0xffff0000u);
            float l4 = f4 - asf(hi.u.z << 16), l5 = f5 - asf(hi.u.z & 0xffff0000u);
            float l6 = f6 - asf(hi.u.w << 16), l7 = f7 - asf(hi.u.w & 0xffff0000u);
            lo.u.x = pk2(l0, l1); lo.u.y = pk2(l2, l3); lo.u.z = pk2(l4, l5); lo.u.w = pk2(l6, l7);
            #pragma unroll
            for (int icb = 0; icb < 4; ++icb) {
                const s8v bf = *(const s8v*)&xb[(icb * 16 + col) * 128 + ((kb * 32 + quad * 8) ^ xsw)];
                acc[icb] = __builtin_amdgcn_mfma_f32_16x16x32_bf16(hi.v, bf, acc[icb], 0, 0, 0);
                acc[icb] = __builtin_amdgcn_mfma_f32_16x16x32_bf16(lo.v, bf, acc[icb], 0, 0, 0);
            }
        }
        if (mt < 7) {
            int f0 = tid, f1 = tid + 512;
            u16* dst = xgs + ((mt + 1) & 1) * 8192;
            *(uint4*)&dst[(f0 >> 4) * 128 + (((f0 & 15) * 8) ^ (((f0 >> 4) & 7) << 3))] = pf0;
            *(uint4*)&dst[(f1 >> 4) * 128 + (((f1 & 15) * 8) ^ (((f1 >> 4) & 7) << 3))] = pf1;
        }
        __syncthreads();
    }

    // ---- y -> LDS as packed bf16 hi|lo ----
    #pragma unroll
    for (int icb = 0; icb < 4; ++icb)
        #pragma unroll
        for (int reg = 0; reg < 4; ++reg) {
            float f = acc[icb][reg];
            u32 h = pk2(f, f) & 0xffffu;
            float lo = f - asf(h << 16);
            u32 l = pk2(lo, lo) & 0xffffu;
            ylds[(icb * 16 + col) * 129 + nb + quad * 4 + reg] = h | (l << 16);
        }
    __syncthreads();

    // ---- matmul2: out[co][n] = w2 x y ----
    f4v acc2[8] = {};
    #pragma unroll
    for (int kb = 0; kb < 2; ++kb) {
        u32 yv[8];
        #pragma unroll
        for (int j = 0; j < 8; ++j)
            yv[j] = ylds[(kb * 32 + quad * 8 + j) * 129 + nb + col];
        U8 bhi, blo;
        bhi.u.x = (yv[0] & 0xffffu) | (yv[1] << 16);
        bhi.u.y = (yv[2] & 0xffffu) | (yv[3] << 16);
        bhi.u.z = (yv[4] & 0xffffu) | (yv[5] << 16);
        bhi.u.w = (yv[6] & 0xffffu) | (yv[7] << 16);
        blo.u.x = (yv[0] >> 16) | (yv[1] & 0xffff0000u);
        blo.u.y = (yv[2] >> 16) | (yv[3] & 0xffff0000u);
        blo.u.z = (yv[4] >> 16) | (yv[5] & 0xffff0000u);
        blo.u.w = (yv[6] >> 16) | (yv[7] & 0xffff0000u);
        #pragma unroll
        for (int cob = 0; cob < 8; ++cob) {
            const s8v a = *(const s8v*)&w2t[(cob * 16 + col) * 64 + ((kb * 32 + quad * 8) ^ xsw)];
            acc2[cob] = __builtin_amdgcn_mfma_f32_16x16x32_bf16(a, bhi.v, acc2[cob], 0, 0, 0);
            acc2[cob] = __builtin_amdgcn_mfma_f32_16x16x32_bf16(a, blo.v, acc2[cob], 0, 0, 0);
        }
    }
    __syncthreads();   // xgs/w2t/ylds dead; ytr region free

    // ---- stage acc2 -> ytr[co][132 n] ----
    #pragma unroll
    for (int cob = 0; cob < 8; ++cob)
        #pragma unroll
        for (int reg = 0; reg < 4; ++reg)
            ytr[(cob * 16 + quad * 4 + reg) * 132 + nb + col] = acc2[cob][reg];
    __syncthreads();

    // ---- coalesced epilogue: float4 RMW over [128 co][128 n] tile ----
    const int n0g = nt * 128;
    #pragma unroll
    for (int it = 0; it < 8; ++it) {
        int f = tid + 512 * it;            // 4096 float4 tasks
        int co = f >> 5, nq = (f & 31) * 4;
        size_t gi = ((size_t)(b * Cn + co)) * Nn + n0g + nq;
        float4 xv = *(const float4*)&x[gi];
        float4 yv = *(const float4*)&ytr[co * 132 + nq];
        float s = sc0[co], bsv = sc1[co];
        float4 o;
        o.x = yv.x * s + bsv + xv.x;
        o.y = yv.y * s + bsv + xv.y;
        o.z = yv.z * s + bsv + xv.z;
        o.w = yv.w * s + bsv + xv.w;
        *(float4*)&out[gi] = o;
    }
}

// ---------------------------------------------------------------------------
extern "C" void kernel_launch(void* const* d_in, const int* in_sizes, int n_in,
                              void* d_out, int out_size, void* d_ws, size_t ws_size,
                              hipStream_t stream)
{
    const float* x  = (const float*)d_in[0];
    const float* w1 = (const float*)d_in[1];
    const float* b1 = (const float*)d_in[2];
    const float* w3 = (const float*)d_in[3];
    const float* b3 = (const float*)d_in[4];
    const float* w4 = (const float*)d_in[5];
    const float* b4 = (const float*)d_in[6];
    const float* w5 = (const float*)d_in[7];
    const float* w2 = (const float*)d_in[8];
    const float* b2 = (const float*)d_in[9];
    const float* gm = (const float*)d_in[10];
    const float* bt = (const float*)d_in[11];
    const float* mn = (const float*)d_in[12];
    const float* vr = (const float*)d_in[13];
    float* out = (float*)d_out;

    float* ws = (float*)d_ws;
    const size_t FTOT = 3823872;           // floats (~15.3 MB) — same reservation
    if (ws_size < FTOT * sizeof(float)) return;

    float* t_w  = ws;                      // 32768 fl
    float* p_w  = ws + 32768;              // 8192 fl
    u16*   xg_w = (u16*)(ws + 40960);      // 65536 u16 = 32768 fl

    k_conv<<<dim3(64, 8), 256, 0, stream>>>(x, w1, b1, w3, b3, w4, b4, w5,
                                            t_w, p_w, xg_w);
    k_back<<<dim3(32, 8), 512, 0, stream>>>(x, t_w, p_w, xg_w,
                                            w2, b2, gm, bt, mn, vr, out);
}

// Round 9
// 116.291 us; speedup vs baseline: 1.0264x; 1.0264x over previous
//
#include <hip/hip_runtime.h>

typedef unsigned int u32;
typedef unsigned short u16;

#define Cn 128
#define ICn 64
#define Nn 4096
#define Mn 1024

typedef __attribute__((ext_vector_type(8))) short s8v;   // 8 bf16 (4 VGPRs)
typedef __attribute__((ext_vector_type(4))) float f4v;   // 4 fp32 acc

union U8 { uint4 u; s8v v; };

__device__ __forceinline__ float asf(u32 u){ union{u32 i; float f;} v; v.i = u; return v.f; }
__device__ __forceinline__ float bf2f(u16 u){ return asf(((u32)u) << 16); }
// HW packed f32->bf16 (RNE)
__device__ __forceinline__ u32 pk2(float lo, float hi){
    u32 r;
    asm("v_cvt_pk_bf16_f32 %0, %1, %2" : "=v"(r) : "v"(lo), "v"(hi));
    return r;
}
__device__ __forceinline__ u16 f2bf(float f){ return (u16)pk2(f, f); }

// ---------------------------------------------------------------------------
// K1: per (row-pair r, half-width wb, batch b):
//   stage x^T bf16 (swizzled), W1/W4 bf16, u3 = w5[:64].W3;
//   dual conv MFMA -> pool a1 -> xg_o (bf16, *(1/1024) fold), pool a4 -> p_o;
//   t_o = u3.x + c3.
// R9 change: p-dot parallelized over all 256 threads (was 16 thr x 64 serial).
// ---------------------------------------------------------------------------
__global__ __launch_bounds__(256) void k_conv(
    const float* __restrict__ x,
    const float* __restrict__ w1, const float* __restrict__ b1,
    const float* __restrict__ w3, const float* __restrict__ b3,
    const float* __restrict__ w4, const float* __restrict__ b4,
    const float* __restrict__ w5,
    float* __restrict__ t_o, float* __restrict__ p_o, u16* __restrict__ xg_o)
{
    const int tile = blockIdx.x;   // 0..63
    const int r  = tile >> 1;      // row-pair 0..31
    const int wb = tile & 1;       // half-width 0..1
    const int b  = blockIdx.y;
    const int tid = threadIdx.x;

    __shared__ __align__(16) u16 smem[35080];
    u16* xsT = smem;                    // [64][136]
    u16* w1t = smem + 8704;             // [64][136]
    u16* w4t = smem + 17408;            // [64][136]
    float* u3s = (float*)&smem[26112];  // [129]
    float* ph0 = (float*)&smem[26372];  // [32][68]
    float* ph1 = (float*)&smem[30724];  // [32][68]

    // ---- stage x^T as bf16 channel-pairs, swizzled ----
    #pragma unroll
    for (int it = 0; it < 4; ++it) {
        int f = tid + 256 * it;        // 1024 tasks: cp = f>>4, rem = f&15
        int cp = f >> 4, rem = f & 15;
        int rl = rem >> 3, wq = rem & 7;
        const float* src = x + ((size_t)(b * Cn + 2 * cp)) * Nn + (2 * r + rl) * 64 + 32 * wb + 4 * wq;
        float4 v0 = *(const float4*)src;
        float4 v1 = *(const float4*)(src + Nn);
        int lp0 = rl * 32 + 4 * wq;
        int cS = (2 * cp) ^ (wq << 3);
        *(u32*)&xsT[(lp0 + 0) * 136 + cS] = pk2(v0.x, v1.x);
        *(u32*)&xsT[(lp0 + 1) * 136 + cS] = pk2(v0.y, v1.y);
        *(u32*)&xsT[(lp0 + 2) * 136 + cS] = pk2(v0.z, v1.z);
        *(u32*)&xsT[(lp0 + 3) * 136 + cS] = pk2(v0.w, v1.w);
    }
    // ---- stage W1, W4 ----
    #pragma unroll
    for (int it = 0; it < 4; ++it) {
        int f = tid + 256 * it;        // 1024 groups of 8: ic = f>>4, cq = f&15
        int ic = f >> 4, cq = f & 15;
        const float4* s1 = (const float4*)&w1[f * 8];
        const float4* s4 = (const float4*)&w4[f * 8];
        float4 a0 = s1[0], a1v = s1[1];
        float4 d0 = s4[0], d1v = s4[1];
        uint4 A, D;
        A.x = pk2(a0.x, a0.y); A.y = pk2(a0.z, a0.w); A.z = pk2(a1v.x, a1v.y); A.w = pk2(a1v.z, a1v.w);
        D.x = pk2(d0.x, d0.y); D.y = pk2(d0.z, d0.w); D.z = pk2(d1v.x, d1v.y); D.w = pk2(d1v.z, d1v.w);
        *(uint4*)&w1t[ic * 136 + 8 * cq] = A;
        *(uint4*)&w4t[ic * 136 + 8 * cq] = D;
    }
    // ---- u3 = w5[:64].W3 ----
    if (tid < 128) {
        float s0 = 0.f, s1 = 0.f;
        #pragma unroll 8
        for (int ic = 0; ic < 64; ic += 2) {
            s0 += w5[ic]     * w3[ic * Cn + tid];
            s1 += w5[ic + 1] * w3[(ic + 1) * Cn + tid];
        }
        u3s[tid] = s0 + s1;
    } else if (tid == 128) {
        float s = 0.f;
        #pragma unroll 16
        for (int ic = 0; ic < 64; ++ic) s += w5[ic] * b3[ic];
        u3s[128] = s;
    }
    __syncthreads();

    const int lane = tid & 63;
    const int wv   = tid >> 6;
    const int col  = lane & 15;
    const int quad = lane >> 4;

    // ---- dual conv MFMA: D[ic][lp] ----
    f4v acc1[4] = {}, acc4[4] = {};
    const u16* xrow = &xsT[(16 * wv + col) * 136];
    const int xsw = (((16 * wv + col) >> 2) & 7) << 3;
    #pragma unroll
    for (int kb = 0; kb < 4; ++kb) {
        s8v bx = *(const s8v*)&xrow[(kb * 32 + quad * 8) ^ xsw];
        #pragma unroll
        for (int icb = 0; icb < 4; ++icb) {
            s8v a1 = *(const s8v*)&w1t[(icb * 16 + col) * 136 + kb * 32 + quad * 8];
            s8v a4 = *(const s8v*)&w4t[(icb * 16 + col) * 136 + kb * 32 + quad * 8];
            acc1[icb] = __builtin_amdgcn_mfma_f32_16x16x32_bf16(a1, bx, acc1[icb], 0, 0, 0);
            acc4[icb] = __builtin_amdgcn_mfma_f32_16x16x32_bf16(a4, bx, acc4[icb], 0, 0, 0);
        }
    }

    // ---- both horizontal pair-max pools (a1->ph0, a4->ph1), one phase ----
    const int lp = 16 * wv + col;
    const int rl = lp >> 5, wl = lp & 31, pw = wl >> 1;
    const bool wr = (wl & 1) == 0;
    #pragma unroll
    for (int icb = 0; icb < 4; ++icb)
        #pragma unroll
        for (int reg = 0; reg < 4; ++reg) {
            float v1 = acc1[icb][reg];
            float m1 = fmaxf(v1, __shfl_xor(v1, 1, 64));
            float v4 = acc4[icb][reg];
            float m4 = fmaxf(v4, __shfl_xor(v4, 1, 64));
            if (wr) {
                ph0[(rl * 16 + pw) * 68 + icb * 16 + quad * 4 + reg] = m1;
                ph1[(rl * 16 + pw) * 68 + icb * 16 + quad * 4 + reg] = m4;
            }
        }
    __syncthreads();   // MFMA LDS reads done + ph ready

    // ---- xg_o = (vpool(a1) + b1) / 1024 as bf16 ----
    #pragma unroll
    for (int it = 0; it < 4; ++it) {
        int e = tid + 256 * it;        // 1024: pwq = e>>6, ic = e&63
        int pwq = e >> 6, ic = e & 63;
        float v = fmaxf(ph0[pwq * 68 + ic], ph0[(16 + pwq) * 68 + ic]) + b1[ic];
        xg_o[((size_t)(b * 64 + ic) << 10) + r * 32 + wb * 16 + pwq] = f2bf(v * (1.0f / 1024.0f));
    }
    // ---- t = u3.x + c3, all 256 threads (4 lanes per pixel) ----
    {
        int px = tid >> 2, part = tid & 3;
        const int tsw = ((px >> 2) & 7) << 3;
        const u16* xr = &xsT[px * 136];
        float s = 0.f;
        #pragma unroll
        for (int cq = 0; cq < 4; ++cq) {
            int u = part * 32 + cq * 8;
            s8v xv = *(const s8v*)&xr[u ^ tsw];
            #pragma unroll
            for (int j = 0; j < 8; ++j) s += u3s[u + j] * bf2f((u16)xv[j]);
        }
        s += __shfl_xor(s, 1, 64);
        s += __shfl_xor(s, 2, 64);
        if (part == 0)
            t_o[(size_t)b * Nn + (2 * r + (px >> 5)) * 64 + 32 * wb + (px & 31)] = s + u3s[128];
    }
    // ---- p from a4 pool: all 256 threads (16 lanes per pw, shfl reduce) ----
    {
        int pwq = tid >> 4, j16 = tid & 15;
        float s = 0.f;
        #pragma unroll
        for (int jj = 0; jj < 4; ++jj) {
            int ic = j16 + 16 * jj;
            float pv = fmaxf(ph1[pwq * 68 + ic], ph1[(16 + pwq) * 68 + ic]) + b4[ic];
            s += w5[64 + ic] * pv;
        }
        s += __shfl_xor(s, 1, 64);
        s += __shfl_xor(s, 2, 64);
        s += __shfl_xor(s, 4, 64);
        s += __shfl_xor(s, 8, 64);
        if (j16 == 0)
            p_o[(size_t)b * Mn + r * 32 + wb * 16 + pwq] = s;
    }
}

// ---------------------------------------------------------------------------
// K2: grid (64 n-tiles, 8 b) x 256 thr (4 waves), n-tile = 64.
// R9 change: half n-tile -> LDS ~72 KB -> 2 blocks/CU (was 1 @ 87.8 KB);
// barriers sync 4 waves; resident pair hides each other's stalls.
// matmul1 (feats hi+lo x xg, dbuf) -> y packed bf16 hi/lo -> matmul2 (w2 x y)
// -> ytr f32 LDS -> coalesced float4 RMW epilogue.
// LDS: xgs 2x16K @0 | w2t 16K @32768 | ylds u32[64][68] @49152 |
//      pl @66560 | tl @70656 | sc0 @70912 | sc1 @71424  (71936 B)
//      ytr f32[128][68] overlays @0 (34816 B, xgs/w2t dead)
// ---------------------------------------------------------------------------
__global__ __launch_bounds__(256) void k_back(
    const float* __restrict__ x, const float* __restrict__ t,
    const float* __restrict__ p, const u16* __restrict__ xg,
    const float* __restrict__ w2, const float* __restrict__ b2,
    const float* __restrict__ gamma, const float* __restrict__ beta,
    const float* __restrict__ mean, const float* __restrict__ var,
    float* __restrict__ out)
{
    const int nt = blockIdx.x;     // 0..63
    const int b  = blockIdx.y;
    const int tid = threadIdx.x;

    __shared__ __align__(16) char smem[71936];
    u16* xgs  = (u16*)smem;                  // [2][64*128]
    u16* w2t  = (u16*)(smem + 32768);        // [128*64]
    u32* ylds = (u32*)(smem + 49152);        // [64][68]
    float* pl = (float*)(smem + 66560);      // [1024]
    float* tl = (float*)(smem + 70656);      // [64]
    float* sc0 = (float*)(smem + 70912);     // [128]
    float* sc1 = (float*)(smem + 71424);     // [128]
    float* ytr = (float*)smem;               // epilogue: [128][68] f32

    // ---- phase 0 staging ----
    #pragma unroll
    for (int it = 0; it < 4; ++it) pl[tid + 256 * it] = p[b * Mn + tid + 256 * it];
    if (tid < 64) {
        tl[tid] = t[(size_t)b * Nn + nt * 64 + tid];
    } else if (tid >= 128) {
        int co = tid - 128;
        float s = gamma[co] * rsqrtf(var[co] + 1e-5f);
        sc0[co] = s;
        sc1[co] = (b2[co] - mean[co]) * s + beta[co];
    }
    #pragma unroll
    for (int it = 0; it < 4; ++it) {
        int f = tid + 256 * it;            // 1024 chunks: co = f>>3, iq = f&7
        int co = f >> 3, iq = f & 7;
        const float4* s2 = (const float4*)&w2[co * 64 + iq * 8];
        float4 a0 = s2[0], a1v = s2[1];
        uint4 V;
        V.x = pk2(a0.x, a0.y); V.y = pk2(a0.z, a0.w); V.z = pk2(a1v.x, a1v.y); V.w = pk2(a1v.z, a1v.w);
        *(uint4*)&w2t[co * 64 + ((iq * 8) ^ ((co & 7) << 3))] = V;
    }
    #pragma unroll
    for (int it = 0; it < 4; ++it) {
        int f = tid + 256 * it;            // 1024 chunks: ic = f>>4, mc = f&15
        int ic = f >> 4, mc = f & 15;
        uint4 V = *(const uint4*)&xg[((size_t)(b * 64 + ic) << 10) + mc * 8];
        *(uint4*)&xgs[ic * 128 + ((mc * 8) ^ ((ic & 7) << 3))] = V;
    }
    __syncthreads();

    const int lane = tid & 63;
    const int wv   = tid >> 6;         // 0..3
    const int col  = lane & 15;
    const int quad = lane >> 4;
    const int nb   = wv * 16;
    const int xsw  = (col & 7) << 3;
    const float tval = tl[nb + col];

    // ---- matmul1: y[n][ic] += (hi+lo)(feats) x xg, m-tiles of 128, dbuf ----
    f4v acc[4] = {};
    for (int mt = 0; mt < 8; ++mt) {
        uint4 pf[4];
        if (mt < 7) {
            #pragma unroll
            for (int j = 0; j < 4; ++j) {
                int f = tid + 256 * j;
                pf[j] = *(const uint4*)&xg[((size_t)(b * 64 + (f >> 4)) << 10) + (mt + 1) * 128 + (f & 15) * 8];
            }
        }
        const u16* xb = xgs + (mt & 1) * 8192;
        #pragma unroll
        for (int kb = 0; kb < 4; ++kb) {
            int mb = mt * 128 + kb * 32;
            float4 pa = *(const float4*)&pl[mb + quad * 8];
            float4 pb = *(const float4*)&pl[mb + quad * 8 + 4];
            float f0 = fmaxf(tval + pa.x, 0.f), f1 = fmaxf(tval + pa.y, 0.f);
            float f2 = fmaxf(tval + pa.z, 0.f), f3 = fmaxf(tval + pa.w, 0.f);
            float f4 = fmaxf(tval + pb.x, 0.f), f5 = fmaxf(tval + pb.y, 0.f);
            float f6 = fmaxf(tval + pb.z, 0.f), f7 = fmaxf(tval + pb.w, 0.f);
            U8 hi, lo;
            hi.u.x = pk2(f0, f1); hi.u.y = pk2(f2, f3); hi.u.z = pk2(f4, f5); hi.u.w = pk2(f6, f7);
            float l0 = f0 - asf(hi.u.x << 16), l1 = f1 - asf(hi.u.x & 0xffff0000u);
            float l2 = f2 - asf(hi.u.y << 16), l3 = f3 - asf(hi.u.y & 0xffff0000u);
            float l4 = f4 - asf(hi.u.z << 16), l5 = f5 - asf(hi.u.z & 0xffff0000u);
            float l6 = f6 - asf(hi.u.w << 16), l7 = f7 - asf(hi.u.w & 0xffff0000u);
            lo.u.x = pk2(l0, l1); lo.u.y = pk2(l2, l3); lo.u.z = pk2(l4, l5); lo.u.w = pk2(l6, l7);
            #pragma unroll
            for (int icb = 0; icb < 4; ++icb) {
                const s8v bf = *(const s8v*)&xb[(icb * 16 + col) * 128 + ((kb * 32 + quad * 8) ^ xsw)];
                acc[icb] = __builtin_amdgcn_mfma_f32_16x16x32_bf16(hi.v, bf, acc[icb], 0, 0, 0);
                acc[icb] = __builtin_amdgcn_mfma_f32_16x16x32_bf16(lo.v, bf, acc[icb], 0, 0, 0);
            }
        }
        if (mt < 7) {
            u16* dst = xgs + ((mt + 1) & 1) * 8192;
            #pragma unroll
            for (int j = 0; j < 4; ++j) {
                int f = tid + 256 * j;
                *(uint4*)&dst[(f >> 4) * 128 + (((f & 15) * 8) ^ (((f >> 4) & 7) << 3))] = pf[j];
            }
        }
        __syncthreads();
    }

    // ---- y -> LDS as packed bf16 hi|lo: ylds[ic][n] ----
    #pragma unroll
    for (int icb = 0; icb < 4; ++icb)
        #pragma unroll
        for (int reg = 0; reg < 4; ++reg) {
            float f = acc[icb][reg];
            u32 h = pk2(f, f) & 0xffffu;
            float lo = f - asf(h << 16);
            u32 l = pk2(lo, lo) & 0xffffu;
            ylds[(icb * 16 + col) * 68 + nb + quad * 4 + reg] = h | (l << 16);
        }
    __syncthreads();

    // ---- matmul2: out[co][n] = w2 x y ----
    f4v acc2[8] = {};
    #pragma unroll
    for (int kb = 0; kb < 2; ++kb) {
        u32 yv[8];
        #pragma unroll
        for (int j = 0; j < 8; ++j)
            yv[j] = ylds[(kb * 32 + quad * 8 + j) * 68 + nb + col];
        U8 bhi, blo;
        bhi.u.x = (yv[0] & 0xffffu) | (yv[1] << 16);
        bhi.u.y = (yv[2] & 0xffffu) | (yv[3] << 16);
        bhi.u.z = (yv[4] & 0xffffu) | (yv[5] << 16);
        bhi.u.w = (yv[6] & 0xffffu) | (yv[7] << 16);
        blo.u.x = (yv[0] >> 16) | (yv[1] & 0xffff0000u);
        blo.u.y = (yv[2] >> 16) | (yv[3] & 0xffff0000u);
        blo.u.z = (yv[4] >> 16) | (yv[5] & 0xffff0000u);
        blo.u.w = (yv[6] >> 16) | (yv[7] & 0xffff0000u);
        #pragma unroll
        for (int cob = 0; cob < 8; ++cob) {
            const s8v a = *(const s8v*)&w2t[(cob * 16 + col) * 64 + ((kb * 32 + quad * 8) ^ xsw)];
            acc2[cob] = __builtin_amdgcn_mfma_f32_16x16x32_bf16(a, bhi.v, acc2[cob], 0, 0, 0);
            acc2[cob] = __builtin_amdgcn_mfma_f32_16x16x32_bf16(a, blo.v, acc2[cob], 0, 0, 0);
        }
    }
    __syncthreads();   // xgs/w2t reads done; ytr region free

    // ---- stage acc2 -> ytr[co][68 n] ----
    #pragma unroll
    for (int cob = 0; cob < 8; ++cob)
        #pragma unroll
        for (int reg = 0; reg < 4; ++reg)
            ytr[(cob * 16 + quad * 4 + reg) * 68 + nb + col] = acc2[cob][reg];
    __syncthreads();

    // ---- coalesced epilogue: float4 RMW over [128 co][64 n] tile ----
    const int n0g = nt * 64;
    #pragma unroll
    for (int it = 0; it < 8; ++it) {
        int f = tid + 256 * it;            // 2048 float4 tasks
        int co = f >> 4, nq = (f & 15) * 4;
        size_t gi = ((size_t)(b * Cn + co)) * Nn + n0g + nq;
        float4 xv = *(const float4*)&x[gi];
        float4 yv = *(const float4*)&ytr[co * 68 + nq];
        float s = sc0[co], bsv = sc1[co];
        float4 o;
        o.x = yv.x * s + bsv + xv.x;
        o.y = yv.y * s + bsv + xv.y;
        o.z = yv.z * s + bsv + xv.z;
        o.w = yv.w * s + bsv + xv.w;
        *(float4*)&out[gi] = o;
    }
}

// ---------------------------------------------------------------------------
extern "C" void kernel_launch(void* const* d_in, const int* in_sizes, int n_in,
                              void* d_out, int out_size, void* d_ws, size_t ws_size,
                              hipStream_t stream)
{
    const float* x  = (const float*)d_in[0];
    const float* w1 = (const float*)d_in[1];
    const float* b1 = (const float*)d_in[2];
    const float* w3 = (const float*)d_in[3];
    const float* b3 = (const float*)d_in[4];
    const float* w4 = (const float*)d_in[5];
    const float* b4 = (const float*)d_in[6];
    const float* w5 = (const float*)d_in[7];
    const float* w2 = (const float*)d_in[8];
    const float* b2 = (const float*)d_in[9];
    const float* gm = (const float*)d_in[10];
    const float* bt = (const float*)d_in[11];
    const float* mn = (const float*)d_in[12];
    const float* vr = (const float*)d_in[13];
    float* out = (float*)d_out;

    float* ws = (float*)d_ws;
    const size_t FTOT = 3823872;           // floats (~15.3 MB) — same reservation
    if (ws_size < FTOT * sizeof(float)) return;

    float* t_w  = ws;                      // 32768 fl
    float* p_w  = ws + 32768;              // 8192 fl
    u16*   xg_w = (u16*)(ws + 40960);      // 65536 u16 = 32768 fl

    k_conv<<<dim3(64, 8), 256, 0, stream>>>(x, w1, b1, w3, b3, w4, b4, w5,
                                            t_w, p_w, xg_w);
    k_back<<<dim3(64, 8), 256, 0, stream>>>(x, t_w, p_w, xg_w,
                                            w2, b2, gm, bt, mn, vr, out);
}